// Round 13
// baseline (105.571 us; speedup 1.0000x reference)
//
#include <hip/hip_runtime.h>
#include <hip/hip_bf16.h>
#include <math.h>

#define NSEQ 26
#define NSUP 25
#define LSEQ 46
#define DJ 90
#define H1 180
#define DIN 256
#define TT 1035
#define TTP 1056     // 33*32 keys padded
#define DOUT 128
#define WAY 5
#define SHOT 5
#define LNB 32
#define SQRT_SCALE 0.29730177875068026f   // (1/sqrt(128))^0.5 folded into K (Q and K both)

typedef __attribute__((ext_vector_type(8))) short short8;
typedef __attribute__((ext_vector_type(4))) float f32x4;

__device__ __forceinline__ ushort f2bf(float x) {
    __hip_bfloat16 h = __float2bfloat16(x);
    return *reinterpret_cast<ushort*>(&h);
}

// ---------------- kernel 1: MLP (two relu layers) + positional encoding ----------------
__global__ void mlp_pe_kernel(const float* __restrict__ ss, const float* __restrict__ qsk,
                              const float* __restrict__ w1, const float* __restrict__ b1,
                              const float* __restrict__ w2, const float* __restrict__ b2,
                              float* __restrict__ feat) {
    __shared__ float xs[DJ];
    __shared__ float hs[H1];
    int r = blockIdx.x;
    int seq = r / LSEQ, l = r % LSEQ;
    const float* x = (seq < NSUP) ? (ss + (size_t)(seq * LSEQ + l) * DJ)
                                  : (qsk + (size_t)l * DJ);
    int tid = threadIdx.x;
    if (tid < DJ) xs[tid] = x[tid];
    __syncthreads();
    if (tid < H1) {
        float a = b1[tid];
        for (int k = 0; k < DJ; ++k) a += xs[k] * w1[k * H1 + tid];
        hs[tid] = fmaxf(a, 0.f);
    }
    __syncthreads();
    int d = tid;  // 0..255
    float a = b2[d];
    for (int k = 0; k < H1; ++k) a += hs[k] * w2[k * DIN + d];
    a = fmaxf(a, 0.f);
    int p2 = d & ~1;
    float freq = expf((float)p2 * (-9.210340371976184f / 256.0f));
    float ang = (float)l * freq;
    a += ((d & 1) ? cosf(ang) : sinf(ang)) * 0.1f;
    feat[(size_t)r * DIN + d] = a;
}

// ---------------- kernel 2: per-frame half projections (factorized tuple GEMM) ----------------
__global__ void proj_kernel(const float* __restrict__ feat,
                            const float* __restrict__ kw, const float* __restrict__ vw,
                            float* __restrict__ kp1, float* __restrict__ kp2,
                            float* __restrict__ vp1, float* __restrict__ vp2) {
    __shared__ float fs[DIN];
    int r = blockIdx.x, d = threadIdx.x;  // 128 threads
    fs[d] = feat[(size_t)r * DIN + d];
    fs[d + 128] = feat[(size_t)r * DIN + d + 128];
    __syncthreads();
    float a1 = 0.f, a2 = 0.f, a3 = 0.f, a4 = 0.f;
    for (int k = 0; k < DIN; ++k) {
        float f = fs[k];
        a1 += f * kw[k * DOUT + d];
        a2 += f * kw[(k + DIN) * DOUT + d];
        a3 += f * vw[k * DOUT + d];
        a4 += f * vw[(k + DIN) * DOUT + d];
    }
    size_t o = (size_t)r * DOUT + d;
    kp1[o] = a1; kp2[o] = a2; vp1[o] = a3; vp2[o] = a4;
}

// ---------------- kernel 3: tuple gather + bias + LayerNorm ----------------
// Fragment-ordered bf16 buffers (16B chunks in exact lane-consumption order):
// Kbf2[p][kt][512][8] (key-permuted), Vbf2 (V^T frags), Qbf[qt][256][8].
// Padded slots (t in [TT,TTP)) written ZERO.
__global__ void kv_kernel(const float* __restrict__ kp1, const float* __restrict__ kp2,
                          const float* __restrict__ vp1, const float* __restrict__ vp2,
                          const float* __restrict__ kb, const float* __restrict__ vb,
                          const float* __restrict__ lg, const float* __restrict__ lb,
                          ushort* __restrict__ Qbf, ushort* __restrict__ Kbf2,
                          ushort* __restrict__ Vbf2, float* __restrict__ Vq) {
    int b = blockIdx.x;
    int s = b / TTP, t = b % TTP;
    int d = threadIdx.x;  // 128 threads
    int kc = d >> 5, gk = (d >> 3) & 3, ek = d & 7;

    if (t >= TT) {
        if (s < NSUP) {
            int kt = t >> 5, jq = t & 31;
            int pos = (jq & 4) ? (16 + ((jq >> 3) << 2) + (jq & 3))
                               : (((jq >> 3) << 2) + (jq & 3));
            Kbf2[(((size_t)s * 33 + kt) * 512 + (size_t)(kc * 2 + (pos >> 4)) * 64 + gk * 16 + (pos & 15)) * 8 + ek] = 0;
            int db = d >> 4, r16v = d & 15, gv = (t & 31) >> 3, ev = t & 7;
            Vbf2[(((size_t)s * 33 + kt) * 512 + (size_t)db * 64 + gv * 16 + r16v) * 8 + ev] = 0;
        } else {
            int qt = t >> 4, r16 = t & 15;
            Qbf[((size_t)qt * 256 + (size_t)kc * 64 + gk * 16 + r16) * 8 + ek] = 0;
        }
        return;
    }

    int i = 0, rem = t;
    while (rem >= (LSEQ - 1 - i)) { rem -= (LSEQ - 1 - i); ++i; }
    int j = i + 1 + rem;
    size_t fi = (size_t)(s * LSEQ + i) * DOUT + d;
    size_t fj = (size_t)(s * LSEQ + j) * DOUT + d;
    float kv = kp1[fi] + kp2[fj] + kb[d];
    float vv = vp1[fi] + vp2[fj] + vb[d];
    float sum = kv, sq = kv * kv;
    for (int off = 32; off >= 1; off >>= 1) {
        sum += __shfl_down(sum, off);
        sq  += __shfl_down(sq, off);
    }
    __shared__ float red[4];
    int wid = d >> 6, lane = d & 63;
    if (lane == 0) { red[wid * 2] = sum; red[wid * 2 + 1] = sq; }
    __syncthreads();
    sum = red[0] + red[2]; sq = red[1] + red[3];
    float m = sum * (1.f / DOUT);
    float var = sq * (1.f / DOUT) - m * m;
    float rs = rsqrtf(var + 1e-5f);
    float kn = ((kv - m) * rs * lg[d] + lb[d]) * SQRT_SCALE;

    if (s < NSUP) {
        int kt = t >> 5, jq = t & 31;
        int pos = (jq & 4) ? (16 + ((jq >> 3) << 2) + (jq & 3))
                           : (((jq >> 3) << 2) + (jq & 3));
        Kbf2[(((size_t)s * 33 + kt) * 512 + (size_t)(kc * 2 + (pos >> 4)) * 64 + gk * 16 + (pos & 15)) * 8 + ek] = f2bf(kn);
        int db = d >> 4, r16v = d & 15, gv = (t & 31) >> 3, ev = t & 7;
        Vbf2[(((size_t)s * 33 + kt) * 512 + (size_t)db * 64 + gv * 16 + r16v) * 8 + ev] = f2bf(vv);
    } else {
        int qt = t >> 4, r16 = t & 15;
        Qbf[((size_t)qt * 256 + (size_t)kc * 64 + gk * 16 + r16) * 8 + ek] = f2bf(kn);
        Vq[(size_t)t * DOUT + d] = vv;
    }
}

// ---------------- kernel 4: MFMA flash attention, 2 q-tiles/wave + global_load_lds ----------------
// Block = 4 waves x 2 q-tiles = 128 q rows of one pair; 225 blocks total.
// Per key-tile: K+V (16KB) staged ONCE via global_load_lds (DMA, no VGPR
// round-trip); each ds_read_b128 fragment feeds 4 MFMAs (2 q-tiles x 2
// score-halves) -> LDS-read redundancy halved vs r12; ONE barrier per tile
// (pre-barrier vmcnt drain covers the DMA). P in-register (permuted-K trick),
// fixed-max softmax, no split-K combine.
__global__ __launch_bounds__(256) void attn_mfma_kernel(
        const ushort* __restrict__ Qbf, const ushort* __restrict__ Kbf2,
        const ushort* __restrict__ Vbf2, float* __restrict__ Obuf) {
    __shared__ __align__(16) ushort Kl[2][4096];
    __shared__ __align__(16) ushort Vl[2][4096];

    // bijective XCD-chunk swizzle (nwg=225, nwg%8=1)
    const int nwg = 9 * NSUP;
    int orig = blockIdx.x;
    int cq = nwg >> 3, cr = nwg & 7;           // 28, 1
    int xcd = orig & 7, sub = orig >> 3;
    int wg = (xcd < cr ? xcd * (cq + 1) : cr * (cq + 1) + (xcd - cr) * cq) + sub;
    int p = wg / 9;
    int qg8 = wg % 9;                           // group of 8 q-tiles

    int tid = threadIdx.x, wid = tid >> 6, lane = tid & 63;
    int g = lane >> 4, r16 = lane & 15;
    int qtA = qg8 * 8 + wid * 2;                // this wave's q-tiles: qtA, qtA+1
    int qtB = qtA + 1;

    const short8 z8 = (short8){0, 0, 0, 0, 0, 0, 0, 0};
    short8 qfA[4], qfB[4];
    {
        const ushort* QbA = Qbf + (size_t)qtA * 2048;
        const ushort* QbB = Qbf + (size_t)qtB * 2048;
        bool okA = qtA < 66, okB = qtB < 66;    // Qbf valid for qt<66, rest zero
        #pragma unroll
        for (int kc = 0; kc < 4; ++kc) {
            qfA[kc] = okA ? *(const short8*)(QbA + (kc * 64 + lane) * 8) : z8;
            qfB[kc] = okB ? *(const short8*)(QbB + (kc * 64 + lane) * 8) : z8;
        }
    }

    // staging split: wave0 K[0:2KB), wave1 K[2KB:4KB), wave2 V[0:2KB), wave3 V[2KB:)
    const ushort* gsrc = ((wid < 2) ? Kbf2 : Vbf2) + (size_t)p * 33 * 4096 + (size_t)(wid & 1) * 2048;
    ushort* l0 = ((wid < 2) ? &Kl[0][0] : &Vl[0][0]) + (wid & 1) * 2048;
    ushort* l1 = ((wid < 2) ? &Kl[1][0] : &Vl[1][0]) + (wid & 1) * 2048;

    f32x4 oA[8], oB[8];
    #pragma unroll
    for (int i = 0; i < 8; ++i) { oA[i] = (f32x4){0.f, 0.f, 0.f, 0.f}; oB[i] = oA[i]; }
    float laccA = 0.f, laccB = 0.f;

    // prologue: DMA-stage tile 0
    #pragma unroll
    for (int c = 0; c < 4; ++c)
        __builtin_amdgcn_global_load_lds(
            (const __attribute__((address_space(1))) void*)(gsrc + c * 512 + lane * 8),
            (__attribute__((address_space(3))) void*)(l0 + c * 512), 16, 0, 0);
    __syncthreads();   // compiler drains vmcnt before s_barrier

    for (int jj = 0; jj < 33; ++jj) {
        const ushort* Kc = &Kl[jj & 1][0];
        const ushort* Vc = &Vl[jj & 1][0];
        if (jj + 1 < 33) {   // DMA next tile into the other buffer (lands by barrier)
            const ushort* s = gsrc + (size_t)(jj + 1) * 4096;
            ushort* dst = ((jj + 1) & 1) ? l1 : l0;
            #pragma unroll
            for (int c = 0; c < 4; ++c)
                __builtin_amdgcn_global_load_lds(
                    (const __attribute__((address_space(1))) void*)(s + c * 512 + lane * 8),
                    (__attribute__((address_space(3))) void*)(dst + c * 512), 16, 0, 0);
        }
        f32x4 s0A = (f32x4){0.f, 0.f, 0.f, 0.f}, s1A = s0A, s0B = s0A, s1B = s0A;
        __builtin_amdgcn_s_setprio(1);
        #pragma unroll
        for (int kc = 0; kc < 4; ++kc) {
            short8 kf0 = *(const short8*)(Kc + ((kc * 2 + 0) * 64 + lane) * 8);
            short8 kf1 = *(const short8*)(Kc + ((kc * 2 + 1) * 64 + lane) * 8);
            s0A = __builtin_amdgcn_mfma_f32_16x16x32_bf16(kf0, qfA[kc], s0A, 0, 0, 0);
            s1A = __builtin_amdgcn_mfma_f32_16x16x32_bf16(kf1, qfA[kc], s1A, 0, 0, 0);
            s0B = __builtin_amdgcn_mfma_f32_16x16x32_bf16(kf0, qfB[kc], s0B, 0, 0, 0);
            s1B = __builtin_amdgcn_mfma_f32_16x16x32_bf16(kf1, qfB[kc], s1B, 0, 0, 0);
        }
        __builtin_amdgcn_s_setprio(0);
        int k0 = jj * 32;
        float aA[8], aB[8];
        if (k0 + 32 > TT) {   // only the final tile
            #pragma unroll
            for (int r = 0; r < 4; ++r) {
                bool v0 = (k0 + 8 * g + r < TT), v1 = (k0 + 8 * g + 4 + r < TT);
                aA[r]     = v0 ? __expf(s0A[r]) : 0.f;
                aA[4 + r] = v1 ? __expf(s1A[r]) : 0.f;
                aB[r]     = v0 ? __expf(s0B[r]) : 0.f;
                aB[4 + r] = v1 ? __expf(s1B[r]) : 0.f;
            }
        } else {
            #pragma unroll
            for (int r = 0; r < 4; ++r) {
                aA[r] = __expf(s0A[r]); aA[4 + r] = __expf(s1A[r]);
                aB[r] = __expf(s0B[r]); aB[4 + r] = __expf(s1B[r]);
            }
        }
        laccA += ((aA[0] + aA[1]) + (aA[2] + aA[3])) + ((aA[4] + aA[5]) + (aA[6] + aA[7]));
        laccB += ((aB[0] + aB[1]) + (aB[2] + aB[3])) + ((aB[4] + aB[5]) + (aB[6] + aB[7]));
        short8 paA, paB;
        #pragma unroll
        for (int e = 0; e < 8; ++e) { paA[e] = (short)f2bf(aA[e]); paB[e] = (short)f2bf(aB[e]); }
        __builtin_amdgcn_s_setprio(1);
        #pragma unroll
        for (int db = 0; db < 8; ++db) {
            short8 vf = *(const short8*)(Vc + (db * 64 + lane) * 8);
            oA[db] = __builtin_amdgcn_mfma_f32_16x16x32_bf16(vf, paA, oA[db], 0, 0, 0);
            oB[db] = __builtin_amdgcn_mfma_f32_16x16x32_bf16(vf, paB, oB[db], 0, 0, 0);
        }
        __builtin_amdgcn_s_setprio(0);
        __syncthreads();   // drains vmcnt (DMA landed) + all reads of buf[cur] done
    }

    // epilogue: per-lane denom (q=r16 of each q-tile), direct store
    laccA += __shfl_xor(laccA, 16); laccA += __shfl_xor(laccA, 32);
    laccB += __shfl_xor(laccB, 16); laccB += __shfl_xor(laccB, 32);
    float invA = 1.f / laccA, invB = 1.f / laccB;
    int qrowA = qtA * 16 + r16, qrowB = qtB * 16 + r16;
    if (qrowA < TT) {
        float* po = Obuf + ((size_t)p * TT + qrowA) * DOUT;
        #pragma unroll
        for (int db = 0; db < 8; ++db) {
            float4 w4 = make_float4(oA[db][0] * invA, oA[db][1] * invA,
                                    oA[db][2] * invA, oA[db][3] * invA);
            *(float4*)&po[db * 16 + g * 4] = w4;
        }
    }
    if (qrowB < TT) {
        float* po = Obuf + ((size_t)p * TT + qrowB) * DOUT;
        #pragma unroll
        for (int db = 0; db < 8; ++db) {
            float4 w4 = make_float4(oB[db][0] * invB, oB[db][1] * invB,
                                    oB[db][2] * invB, oB[db][3] * invB);
            *(float4*)&po[db * 16 + g * 4] = w4;
        }
    }
}

// ---------------- kernel 5: proto = mean over shots ----------------
__global__ void proto_kernel(const float* __restrict__ Obuf, float* __restrict__ proto) {
    int c = blockIdx.y;
    int idx = blockIdx.x * 256 + threadIdx.x;
    if (idx >= TT * DOUT) return;
    float a = 0.f;
    #pragma unroll
    for (int s = 0; s < SHOT; ++s)
        a += Obuf[((size_t)(c * SHOT + s) * TT) * DOUT + idx];
    proto[(size_t)c * TT * DOUT + idx] = a * 0.2f;
}

// ---------------- kernel 6a: logits partial sums ----------------
__global__ __launch_bounds__(256) void logits_partial_kernel(
        const float* __restrict__ Vq, const float* __restrict__ proto,
        float* __restrict__ partial) {
    int c = blockIdx.y, tid = threadIdx.x;
    const float4* qv = (const float4*)Vq;
    const float4* pr = (const float4*)(proto + (size_t)c * TT * DOUT);
    float sum = 0.f;
    const int n4 = TT * DOUT / 4;
    for (int i = blockIdx.x * 256 + tid; i < n4; i += LNB * 256) {
        float4 q = qv[i], p = pr[i];
        float dx = q.x - p.x, dy = q.y - p.y, dz = q.z - p.z, dw = q.w - p.w;
        sum += dx * dx + dy * dy + dz * dz + dw * dw;
    }
    for (int off = 32; off >= 1; off >>= 1) sum += __shfl_down(sum, off);
    __shared__ float red[4];
    int w = tid >> 6, lane = tid & 63;
    if (lane == 0) red[w] = sum;
    __syncthreads();
    if (tid == 0) partial[c * LNB + blockIdx.x] = red[0] + red[1] + red[2] + red[3];
}

// ---------------- kernel 6b: logits finalize ----------------
__global__ void logits_final_kernel(const float* __restrict__ partial, float* __restrict__ out) {
    int c = threadIdx.x;
    if (c < WAY) {
        float s = 0.f;
        #pragma unroll
        for (int b = 0; b < LNB; ++b) s += partial[c * LNB + b];
        out[c] = -s / (float)TT;
    }
}

// ---------------- kernel 7: argmax + is_true = exp(qv - proto[best]) ----------------
__global__ void istrue_kernel(const float* __restrict__ Vq, const float* __restrict__ proto,
                              float* out) {
    float l0 = out[0];
    int best = 0;
    for (int cc = 1; cc < WAY; ++cc) {
        float lc = out[cc];
        if (lc > l0) { l0 = lc; best = cc; }
    }
    const float* pr = proto + (size_t)best * TT * DOUT;
    int idx = blockIdx.x * 256 + threadIdx.x;
    if (idx < TT * DOUT) out[5 + idx] = expf(Vq[idx] - pr[idx]);
}

extern "C" void kernel_launch(void* const* d_in, const int* in_sizes, int n_in,
                              void* d_out, int out_size, void* d_ws, size_t ws_size,
                              hipStream_t stream) {
    const float* ss  = (const float*)d_in[0];
    const float* qsk = (const float*)d_in[1];
    // d_in[2] = ss_labels (sorted balanced; reduces to a reshape)
    const float* w1 = (const float*)d_in[3];
    const float* b1 = (const float*)d_in[4];
    const float* w2 = (const float*)d_in[5];
    const float* b2 = (const float*)d_in[6];
    const float* kw = (const float*)d_in[7];
    const float* kb = (const float*)d_in[8];
    const float* vw = (const float*)d_in[9];
    const float* vb = (const float*)d_in[10];
    const float* lg = (const float*)d_in[11];
    const float* lb = (const float*)d_in[12];
    float* out = (float*)d_out;

    float* w = (float*)d_ws;
    float* feat = w;                                   // 1196*256 f32
    float* kp1  = feat + 1196 * 256;                   // 1196*128 f32 each
    float* kp2  = kp1 + 1196 * 128;
    float* vp1  = kp2 + 1196 * 128;
    float* vp2  = vp1 + 1196 * 128;
    float* Vq   = vp2 + 1196 * 128;                    // TT*128 f32 (query V)
    float* Obuf = Vq + (size_t)TT * DOUT;              // 25*TT*128 f32
    float* proto = Obuf + (size_t)NSUP * TT * DOUT;    // 5*TT*128 f32
    float* partial = proto + (size_t)WAY * TT * DOUT;  // WAY*LNB f32
    ushort* Qbf  = (ushort*)(partial + WAY * LNB);     // 68*2048 u16 (frag-order Q)
    ushort* Kbf2 = Qbf + (size_t)68 * 2048;            // 25*33*4096 u16
    ushort* Vbf2 = Kbf2 + (size_t)NSUP * 33 * 4096;    // 25*33*4096 u16
    // total ~34 MB

    hipLaunchKernelGGL(mlp_pe_kernel, dim3(NSEQ * LSEQ), dim3(256), 0, stream,
                       ss, qsk, w1, b1, w2, b2, feat);
    hipLaunchKernelGGL(proj_kernel, dim3(NSEQ * LSEQ), dim3(128), 0, stream,
                       feat, kw, vw, kp1, kp2, vp1, vp2);
    hipLaunchKernelGGL(kv_kernel, dim3(NSEQ * TTP), dim3(128), 0, stream,
                       kp1, kp2, vp1, vp2, kb, vb, lg, lb, Qbf, Kbf2, Vbf2, Vq);
    hipLaunchKernelGGL(attn_mfma_kernel, dim3(9 * NSUP), dim3(256), 0, stream,
                       Qbf, Kbf2, Vbf2, Obuf);
    hipLaunchKernelGGL(proto_kernel, dim3((TT * DOUT + 255) / 256, WAY), dim3(256), 0, stream,
                       Obuf, proto);
    hipLaunchKernelGGL(logits_partial_kernel, dim3(LNB, WAY), dim3(256), 0, stream,
                       Vq, proto, partial);
    hipLaunchKernelGGL(logits_final_kernel, dim3(1), dim3(64), 0, stream, partial, out);
    hipLaunchKernelGGL(istrue_kernel, dim3((TT * DOUT + 255) / 256), dim3(256), 0, stream,
                       Vq, proto, out);
}

// Round 14
// 95.508 us; speedup vs baseline: 1.1054x; 1.1054x over previous
//
#include <hip/hip_runtime.h>
#include <hip/hip_bf16.h>
#include <math.h>

#define NSEQ 26
#define NSUP 25
#define LSEQ 46
#define DJ 90
#define H1 180
#define DIN 256
#define TT 1035
#define TTP 1056     // 33*32 keys padded
#define DOUT 128
#define WAY 5
#define SHOT 5
#define LNB 32
#define PROWS 4      // proj rows per block (1196 = 4*299)
#define SQRT_SCALE 0.29730177875068026f   // (1/sqrt(128))^0.5 folded into K (Q and K both)

typedef __attribute__((ext_vector_type(8))) short short8;
typedef __attribute__((ext_vector_type(4))) float f32x4;

__device__ __forceinline__ ushort f2bf(float x) {
    __hip_bfloat16 h = __float2bfloat16(x);
    return *reinterpret_cast<ushort*>(&h);
}

// ---------------- kernel 1: MLP (two relu layers) + positional encoding ----------------
__global__ void mlp_pe_kernel(const float* __restrict__ ss, const float* __restrict__ qsk,
                              const float* __restrict__ w1, const float* __restrict__ b1,
                              const float* __restrict__ w2, const float* __restrict__ b2,
                              float* __restrict__ feat) {
    __shared__ float xs[DJ];
    __shared__ float hs[H1];
    int r = blockIdx.x;
    int seq = r / LSEQ, l = r % LSEQ;
    const float* x = (seq < NSUP) ? (ss + (size_t)(seq * LSEQ + l) * DJ)
                                  : (qsk + (size_t)l * DJ);
    int tid = threadIdx.x;
    if (tid < DJ) xs[tid] = x[tid];
    __syncthreads();
    if (tid < H1) {
        float a = b1[tid];
        for (int k = 0; k < DJ; ++k) a += xs[k] * w1[k * H1 + tid];
        hs[tid] = fmaxf(a, 0.f);
    }
    __syncthreads();
    int d = tid;  // 0..255
    float a = b2[d];
    for (int k = 0; k < H1; ++k) a += hs[k] * w2[k * DIN + d];
    a = fmaxf(a, 0.f);
    int p2 = d & ~1;
    float freq = expf((float)p2 * (-9.210340371976184f / 256.0f));
    float ang = (float)l * freq;
    a += ((d & 1) ? cosf(ang) : sinf(ang)) * 0.1f;
    feat[(size_t)r * DIN + d] = a;
}

// ---------------- kernel 2: half projections, 4 rows/block (weight reuse in-block) ----------------
// r13 profile arithmetic: 1196 blocks x 512KB weight re-reads = 612 MB L2 (~18us).
// 4 rows/block -> 153 MB. feat rows in LDS (broadcast reads), weights streamed.
__global__ __launch_bounds__(256) void proj_kernel(
        const float* __restrict__ feat,
        const float* __restrict__ kw, const float* __restrict__ vw,
        float* __restrict__ kp1, float* __restrict__ kp2,
        float* __restrict__ vp1, float* __restrict__ vp2) {
    __shared__ float fs[PROWS][DIN];
    int r0 = blockIdx.x * PROWS;
    int tid = threadIdx.x;
    int d = tid & 127, h = tid >> 7;   // h=0: kw pair, h=1: vw pair
    #pragma unroll
    for (int rr = 0; rr < PROWS; ++rr)
        fs[rr][tid] = feat[(size_t)(r0 + rr) * DIN + tid];
    __syncthreads();
    const float* W = h ? vw : kw;
    float at[PROWS] = {0.f, 0.f, 0.f, 0.f};
    float ab[PROWS] = {0.f, 0.f, 0.f, 0.f};
    for (int k = 0; k < DIN; ++k) {
        float wt = W[k * DOUT + d];
        float wb = W[(k + DIN) * DOUT + d];
        #pragma unroll
        for (int rr = 0; rr < PROWS; ++rr) {
            float f = fs[rr][k];
            at[rr] += f * wt;
            ab[rr] += f * wb;
        }
    }
    #pragma unroll
    for (int rr = 0; rr < PROWS; ++rr) {
        size_t o = (size_t)(r0 + rr) * DOUT + d;
        if (h == 0) { kp1[o] = at[rr]; kp2[o] = ab[rr]; }
        else        { vp1[o] = at[rr]; vp2[o] = ab[rr]; }
    }
}

// ---------------- kernel 3: tuple gather + bias + LayerNorm, block per (seq, key-tile) ----------------
// 858 blocks x 256 thr; 16-lane group owns one tuple x 8 dims. Closed-form
// (i,j) decode (sqrt + fixup) replaces 45-iter serial loop; LN via 4 shfl_xor
// within the 16-lane group. Byte-identical output layout to r12's writer:
// Kbf2[p][kt][512][8] key-permuted, Vbf2 V^T frags, Qbf[qt][256][8], pad=0.
__global__ __launch_bounds__(256) void kv_kernel(
        const float* __restrict__ kp1, const float* __restrict__ kp2,
        const float* __restrict__ vp1, const float* __restrict__ vp2,
        const float* __restrict__ kb, const float* __restrict__ vb,
        const float* __restrict__ lg, const float* __restrict__ lb,
        ushort* __restrict__ Qbf, ushort* __restrict__ Kbf2,
        ushort* __restrict__ Vbf2, float* __restrict__ Vq) {
    int s = blockIdx.x / 33, kt = blockIdx.x % 33;
    int tid = threadIdx.x, wid = tid >> 6, lane = tid & 63;
    int lgrp = lane >> 4, dl = lane & 15;
    int d0 = dl * 8;
    int kc = d0 >> 5, gk = (d0 >> 3) & 3;

    #pragma unroll
    for (int pp = 0; pp < 2; ++pp) {
        int jq = pp * 16 + wid * 4 + lgrp;      // tuple within tile, 0..31
        int t = kt * 32 + jq;
        bool valid = t < TT;
        float kv8[8], vv8[8];
        #pragma unroll
        for (int e = 0; e < 8; ++e) { kv8[e] = 0.f; vv8[e] = 0.f; }
        if (valid) {
            // closed-form decode: before(i) = i*(91-i)/2
            int i = (int)((91.0f - sqrtf((float)(8281 - 8 * t))) * 0.5f);
            while (i > 0 && t < i * (91 - i) / 2) --i;
            while (i < 44 && t >= (i + 1) * (90 - i) / 2) ++i;
            int j = i + 1 + (t - i * (91 - i) / 2);
            const float* ki = kp1 + (size_t)(s * LSEQ + i) * DOUT + d0;
            const float* kj = kp2 + (size_t)(s * LSEQ + j) * DOUT + d0;
            const float* vi = vp1 + (size_t)(s * LSEQ + i) * DOUT + d0;
            const float* vj = vp2 + (size_t)(s * LSEQ + j) * DOUT + d0;
            #pragma unroll
            for (int e = 0; e < 8; ++e) {
                kv8[e] = ki[e] + kj[e] + kb[d0 + e];
                vv8[e] = vi[e] + vj[e] + vb[d0 + e];
            }
        }
        // LayerNorm over 128 dims = 16 lanes x 8
        float sum = 0.f, sq = 0.f;
        #pragma unroll
        for (int e = 0; e < 8; ++e) { sum += kv8[e]; sq += kv8[e] * kv8[e]; }
        sum += __shfl_xor(sum, 1); sq += __shfl_xor(sq, 1);
        sum += __shfl_xor(sum, 2); sq += __shfl_xor(sq, 2);
        sum += __shfl_xor(sum, 4); sq += __shfl_xor(sq, 4);
        sum += __shfl_xor(sum, 8); sq += __shfl_xor(sq, 8);
        float m = sum * (1.f / DOUT);
        float var = sq * (1.f / DOUT) - m * m;
        float rs = rsqrtf(var + 1e-5f);
        short8 kn8;
        #pragma unroll
        for (int e = 0; e < 8; ++e) {
            float kn = valid ? ((kv8[e] - m) * rs * lg[d0 + e] + lb[d0 + e]) * SQRT_SCALE : 0.f;
            kn8[e] = (short)f2bf(kn);
        }
        if (s < NSUP) {
            int pos = (jq & 4) ? (16 + ((jq >> 3) << 2) + (jq & 3))
                               : (((jq >> 3) << 2) + (jq & 3));
            ushort* Ktile = Kbf2 + ((size_t)s * 33 + kt) * 4096;
            *(short8*)(Ktile + (size_t)((kc * 2 + (pos >> 4)) * 64 + gk * 16 + (pos & 15)) * 8) = kn8;
            // V^T fragment scatter: chunk (db, gv=jq>>3, r16v=d&15), elem ev=jq&7
            ushort* Vtile = Vbf2 + ((size_t)s * 33 + kt) * 4096;
            int gv = jq >> 3, ev = jq & 7;
            #pragma unroll
            for (int e = 0; e < 8; ++e) {
                int d = d0 + e, db = d >> 4, r16v = d & 15;
                Vtile[(size_t)(db * 64 + gv * 16 + r16v) * 8 + ev] = valid ? f2bf(vv8[e]) : (ushort)0;
            }
        } else {
            int qt = t >> 4, r16q = t & 15;
            *(short8*)(Qbf + (size_t)qt * 2048 + (size_t)(kc * 64 + gk * 16 + r16q) * 8) = kn8;
            if (valid) {
                float* vq = Vq + (size_t)t * DOUT + d0;
                #pragma unroll
                for (int e = 0; e < 8; ++e) vq[e] = vv8[e];
            }
        }
    }
}

// ---------------- kernel 4: MFMA flash attention (r12 grid + gload_lds single-barrier) ----------------
// 425 blocks (17 q-groups x 25 pairs), 4 waves x 1 q-tile. K+V staged via
// global_load_lds DMA one tile ahead; ONE barrier per tile (drain covers DMA).
// P in-register (permuted-K), fixed-max softmax.
__global__ __launch_bounds__(256) void attn_mfma_kernel(
        const ushort* __restrict__ Qbf, const ushort* __restrict__ Kbf2,
        const ushort* __restrict__ Vbf2, float* __restrict__ Obuf) {
    __shared__ __align__(16) ushort Kl[2][4096];
    __shared__ __align__(16) ushort Vl[2][4096];

    // bijective XCD-chunk swizzle (nwg=425)
    const int nwg = 17 * NSUP;
    int orig = blockIdx.x;
    int cq = nwg >> 3, cr = nwg & 7;           // 53, 1
    int xcd = orig & 7, sub = orig >> 3;
    int wg = (xcd < cr ? xcd * (cq + 1) : cr * (cq + 1) + (xcd - cr) * cq) + sub;
    int p = wg / 17;

    int tid = threadIdx.x, wid = tid >> 6, lane = tid & 63;
    int g = lane >> 4, r16 = lane & 15;
    int qt = (wg % 17) * 4 + wid;              // 0..67 (66,67 masked)

    const short8 z8 = (short8){0, 0, 0, 0, 0, 0, 0, 0};
    short8 qf[4];
    {
        const ushort* Qb = Qbf + (size_t)qt * 2048;
        bool ok = qt < 66;
        #pragma unroll
        for (int kc = 0; kc < 4; ++kc)
            qf[kc] = ok ? *(const short8*)(Qb + (kc * 64 + lane) * 8) : z8;
    }

    // staging split: wave0 K[0:2KB), wave1 K[2KB:4KB), wave2 V[0:2KB), wave3 V[2KB:)
    const ushort* gsrc = ((wid < 2) ? Kbf2 : Vbf2) + (size_t)p * 33 * 4096 + (size_t)(wid & 1) * 2048;
    ushort* l0 = ((wid < 2) ? &Kl[0][0] : &Vl[0][0]) + (wid & 1) * 2048;
    ushort* l1 = ((wid < 2) ? &Kl[1][0] : &Vl[1][0]) + (wid & 1) * 2048;

    f32x4 o[8];
    #pragma unroll
    for (int i = 0; i < 8; ++i) o[i] = (f32x4){0.f, 0.f, 0.f, 0.f};
    float lacc = 0.f;

    #pragma unroll
    for (int c = 0; c < 4; ++c)
        __builtin_amdgcn_global_load_lds(
            (const __attribute__((address_space(1))) void*)(gsrc + c * 512 + lane * 8),
            (__attribute__((address_space(3))) void*)(l0 + c * 512), 16, 0, 0);
    __syncthreads();

    for (int jj = 0; jj < 33; ++jj) {
        const ushort* Kc = &Kl[jj & 1][0];
        const ushort* Vc = &Vl[jj & 1][0];
        if (jj + 1 < 33) {
            const ushort* src = gsrc + (size_t)(jj + 1) * 4096;
            ushort* dst = ((jj + 1) & 1) ? l1 : l0;
            #pragma unroll
            for (int c = 0; c < 4; ++c)
                __builtin_amdgcn_global_load_lds(
                    (const __attribute__((address_space(1))) void*)(src + c * 512 + lane * 8),
                    (__attribute__((address_space(3))) void*)(dst + c * 512), 16, 0, 0);
        }
        f32x4 s0 = (f32x4){0.f, 0.f, 0.f, 0.f}, s1 = s0;
        __builtin_amdgcn_s_setprio(1);
        #pragma unroll
        for (int kc = 0; kc < 4; ++kc) {
            short8 kf0 = *(const short8*)(Kc + ((kc * 2 + 0) * 64 + lane) * 8);
            short8 kf1 = *(const short8*)(Kc + ((kc * 2 + 1) * 64 + lane) * 8);
            s0 = __builtin_amdgcn_mfma_f32_16x16x32_bf16(kf0, qf[kc], s0, 0, 0, 0);
            s1 = __builtin_amdgcn_mfma_f32_16x16x32_bf16(kf1, qf[kc], s1, 0, 0, 0);
        }
        __builtin_amdgcn_s_setprio(0);
        int k0 = jj * 32;
        float a[8];
        if (k0 + 32 > TT) {
            #pragma unroll
            for (int r = 0; r < 4; ++r) {
                a[r]     = (k0 + 8 * g + r < TT)     ? __expf(s0[r]) : 0.f;
                a[4 + r] = (k0 + 8 * g + 4 + r < TT) ? __expf(s1[r]) : 0.f;
            }
        } else {
            #pragma unroll
            for (int r = 0; r < 4; ++r) { a[r] = __expf(s0[r]); a[4 + r] = __expf(s1[r]); }
        }
        lacc += ((a[0] + a[1]) + (a[2] + a[3])) + ((a[4] + a[5]) + (a[6] + a[7]));
        short8 pa;
        #pragma unroll
        for (int e = 0; e < 8; ++e) pa[e] = (short)f2bf(a[e]);
        __builtin_amdgcn_s_setprio(1);
        #pragma unroll
        for (int db = 0; db < 8; ++db) {
            short8 vf = *(const short8*)(Vc + (db * 64 + lane) * 8);
            o[db] = __builtin_amdgcn_mfma_f32_16x16x32_bf16(vf, pa, o[db], 0, 0, 0);
        }
        __builtin_amdgcn_s_setprio(0);
        __syncthreads();   // drains vmcnt (next-tile DMA landed) + WAR on buf
    }

    lacc += __shfl_xor(lacc, 16);
    lacc += __shfl_xor(lacc, 32);
    float invL = 1.f / lacc;
    int qrow = qt * 16 + r16;
    if (qrow < TT) {
        float* po = Obuf + ((size_t)p * TT + qrow) * DOUT;
        #pragma unroll
        for (int db = 0; db < 8; ++db) {
            float4 w4 = make_float4(o[db][0] * invL, o[db][1] * invL,
                                    o[db][2] * invL, o[db][3] * invL);
            *(float4*)&po[db * 16 + g * 4] = w4;
        }
    }
}

// ---------------- kernel 5: proto = mean over shots ----------------
__global__ void proto_kernel(const float* __restrict__ Obuf, float* __restrict__ proto) {
    int c = blockIdx.y;
    int idx = blockIdx.x * 256 + threadIdx.x;
    if (idx >= TT * DOUT) return;
    float a = 0.f;
    #pragma unroll
    for (int s = 0; s < SHOT; ++s)
        a += Obuf[((size_t)(c * SHOT + s) * TT) * DOUT + idx];
    proto[(size_t)c * TT * DOUT + idx] = a * 0.2f;
}

// ---------------- kernel 6a: logits partial sums ----------------
__global__ __launch_bounds__(256) void logits_partial_kernel(
        const float* __restrict__ Vq, const float* __restrict__ proto,
        float* __restrict__ partial) {
    int c = blockIdx.y, tid = threadIdx.x;
    const float4* qv = (const float4*)Vq;
    const float4* pr = (const float4*)(proto + (size_t)c * TT * DOUT);
    float sum = 0.f;
    const int n4 = TT * DOUT / 4;
    for (int i = blockIdx.x * 256 + tid; i < n4; i += LNB * 256) {
        float4 q = qv[i], p = pr[i];
        float dx = q.x - p.x, dy = q.y - p.y, dz = q.z - p.z, dw = q.w - p.w;
        sum += dx * dx + dy * dy + dz * dz + dw * dw;
    }
    for (int off = 32; off >= 1; off >>= 1) sum += __shfl_down(sum, off);
    __shared__ float red[4];
    int w = tid >> 6, lane = tid & 63;
    if (lane == 0) red[w] = sum;
    __syncthreads();
    if (tid == 0) partial[c * LNB + blockIdx.x] = red[0] + red[1] + red[2] + red[3];
}

// ---------------- kernel 6b: logits finalize ----------------
__global__ void logits_final_kernel(const float* __restrict__ partial, float* __restrict__ out) {
    int c = threadIdx.x;
    if (c < WAY) {
        float s = 0.f;
        #pragma unroll
        for (int b = 0; b < LNB; ++b) s += partial[c * LNB + b];
        out[c] = -s / (float)TT;
    }
}

// ---------------- kernel 7: argmax + is_true = exp(qv - proto[best]) ----------------
__global__ void istrue_kernel(const float* __restrict__ Vq, const float* __restrict__ proto,
                              float* out) {
    float l0 = out[0];
    int best = 0;
    for (int cc = 1; cc < WAY; ++cc) {
        float lc = out[cc];
        if (lc > l0) { l0 = lc; best = cc; }
    }
    const float* pr = proto + (size_t)best * TT * DOUT;
    int idx = blockIdx.x * 256 + threadIdx.x;
    if (idx < TT * DOUT) out[5 + idx] = expf(Vq[idx] - pr[idx]);
}

extern "C" void kernel_launch(void* const* d_in, const int* in_sizes, int n_in,
                              void* d_out, int out_size, void* d_ws, size_t ws_size,
                              hipStream_t stream) {
    const float* ss  = (const float*)d_in[0];
    const float* qsk = (const float*)d_in[1];
    // d_in[2] = ss_labels (sorted balanced; reduces to a reshape)
    const float* w1 = (const float*)d_in[3];
    const float* b1 = (const float*)d_in[4];
    const float* w2 = (const float*)d_in[5];
    const float* b2 = (const float*)d_in[6];
    const float* kw = (const float*)d_in[7];
    const float* kb = (const float*)d_in[8];
    const float* vw = (const float*)d_in[9];
    const float* vb = (const float*)d_in[10];
    const float* lg = (const float*)d_in[11];
    const float* lb = (const float*)d_in[12];
    float* out = (float*)d_out;

    float* w = (float*)d_ws;
    float* feat = w;                                   // 1196*256 f32
    float* kp1  = feat + 1196 * 256;                   // 1196*128 f32 each
    float* kp2  = kp1 + 1196 * 128;
    float* vp1  = kp2 + 1196 * 128;
    float* vp2  = vp1 + 1196 * 128;
    float* Vq   = vp2 + 1196 * 128;                    // TT*128 f32 (query V)
    float* Obuf = Vq + (size_t)TT * DOUT;              // 25*TT*128 f32
    float* proto = Obuf + (size_t)NSUP * TT * DOUT;    // 5*TT*128 f32
    float* partial = proto + (size_t)WAY * TT * DOUT;  // WAY*LNB f32
    ushort* Qbf  = (ushort*)(partial + WAY * LNB);     // 68*2048 u16 (frag-order Q)
    ushort* Kbf2 = Qbf + (size_t)68 * 2048;            // 25*33*4096 u16
    ushort* Vbf2 = Kbf2 + (size_t)NSUP * 33 * 4096;    // 25*33*4096 u16
    // total ~34 MB

    hipLaunchKernelGGL(mlp_pe_kernel, dim3(NSEQ * LSEQ), dim3(256), 0, stream,
                       ss, qsk, w1, b1, w2, b2, feat);
    hipLaunchKernelGGL(proj_kernel, dim3(1196 / PROWS), dim3(256), 0, stream,
                       feat, kw, vw, kp1, kp2, vp1, vp2);
    hipLaunchKernelGGL(kv_kernel, dim3(NSEQ * 33), dim3(256), 0, stream,
                       kp1, kp2, vp1, vp2, kb, vb, lg, lb, Qbf, Kbf2, Vbf2, Vq);
    hipLaunchKernelGGL(attn_mfma_kernel, dim3(17 * NSUP), dim3(256), 0, stream,
                       Qbf, Kbf2, Vbf2, Obuf);
    hipLaunchKernelGGL(proto_kernel, dim3((TT * DOUT + 255) / 256, WAY), dim3(256), 0, stream,
                       Obuf, proto);
    hipLaunchKernelGGL(logits_partial_kernel, dim3(LNB, WAY), dim3(256), 0, stream,
                       Vq, proto, partial);
    hipLaunchKernelGGL(logits_final_kernel, dim3(1), dim3(64), 0, stream, partial, out);
    hipLaunchKernelGGL(istrue_kernel, dim3((TT * DOUT + 255) / 256), dim3(256), 0, stream,
                       Vq, proto, out);
}